// Round 20
// baseline (417.554 us; speedup 1.0000x reference)
//
#include <hip/hip_runtime.h>
#include <math.h>

#define DD 128
#define HW 512
#define MG 514

// Verified reference stack (r10/r11/r14): G1 predux-tree colmajor conv,
// contract-off mul/add mag, fd-hybrid classifier.
// r20: register-rolling k_nms with 64-aligned output tiles (r17 pipeline +
// r16 store pattern). No LDS, no barriers, no divisions.

// ---- fdlibm/glibc float atan (bit-exact port) ----
static __device__ float fd_atanf(float x) {
    #pragma clang fp contract(off)
    const unsigned hx = __float_as_uint(x);
    const unsigned ix = hx & 0x7fffffffu;
    const double A0 = 0.46364760900080611621425623146121440203;
    const double A1 = 0.78539816339744830961566084581987572105;
    const double A2 = 0.98279372324732906798571061101466601449;
    const double A3 = 1.57079632679489661923132169163975144210;
    const float aT0 =  3.3333328366e-01f;
    const float aT1 = -1.9999158382e-01f;
    const float aT2 =  1.4253635705e-01f;
    const float aT3 = -1.0648017377e-01f;
    const float aT4 =  6.1687607318e-02f;
    float z, w, s1, s2;
    int id;
    double a;
    if (ix >= 0x4c800000u) {
        a = A3;
        float hi = (float)a; if ((double)hi > a) hi = __uint_as_float(__float_as_uint(hi) - 1u);
        float lo = (float)(a - (double)hi);
        float r = hi + lo;
        return (hx >> 31) ? -r : r;
    }
    if (ix < 0x3ee00000u) {
        if (ix < 0x39800000u) return x;
        id = -1;
    } else {
        x = fabsf(x);
        if (ix < 0x3f980000u) {
            if (ix < 0x3f300000u) { id = 0; x = (2.0f * x - 1.0f) / (2.0f + x); }
            else                  { id = 1; x = (x - 1.0f) / (x + 1.0f); }
        } else {
            if (ix < 0x401c0000u) { id = 2; x = (x - 1.5f) / (1.0f + 1.5f * x); }
            else                  { id = 3; x = -1.0f / x; }
        }
    }
    z = x * x;
    w = z * z;
    s1 = z * (aT0 + w * (aT2 + w * aT4));
    s2 = w * (aT1 + w * aT3);
    if (id < 0) return x - x * (s1 + s2);
    a = (id == 0) ? A0 : (id == 1) ? A1 : (id == 2) ? A2 : A3;
    float hi = (float)a; if ((double)hi > a) hi = __uint_as_float(__float_as_uint(hi) - 1u);
    float lo = (float)(a - (double)hi);
    z = hi - ((x * (s1 + s2) - lo) - x);
    return (hx >> 31) ? -z : z;
}

static __device__ __noinline__ int cls_fd(float y, float x) {
    #pragma clang fp contract(off)
    const unsigned hx = __float_as_uint(x), hy = __float_as_uint(y);
    const unsigned ix = hx & 0x7fffffffu, iy = hy & 0x7fffffffu;
    unsigned m = ((hy >> 31) & 1u) | ((hx >> 30) & 2u);
    const double PI_D = 3.14159265358979323846264338327950288420;
    const float pi_f  = (float)PI_D;
    const float pi_lo = (float)(PI_D - (double)pi_f);
    const float pi4_f = (float)(PI_D / 4.0);
    const float pi2_f = (float)(PI_D / 2.0);
    float v;
    if (iy == 0) {
        v = (m == 0 || m == 1) ? y : (m == 2 ? pi_f : -pi_f);
    } else if (ix == 0) {
        v = (m & 1u) ? -pi2_f : pi2_f;
    } else if (ix + (26u << 23) < iy) {
        v = (m & 1u) ? -pi2_f : pi2_f;
    } else {
        float z;
        if ((m & 2u) && iy + (26u << 23) < ix) z = 0.0f;
        else z = fd_atanf(fabsf(y / x));
        switch (m) {
            case 0:  v = z; break;
            case 1:  v = -z; break;
            case 2:  v = pi_f - (z - pi_lo); break;
            default: v = (z - pi_lo) - pi_f; break;
        }
    }
    float t = v / pi4_f;
    int n = (int)rintf(t);
    return n & 3;
}

static __device__ __forceinline__ int classify(float gx, float gy) {
    #pragma clang fp contract(off)
    float ax = fabsf(gx), ay = fabsf(gy);
    const float T = 0.41421356237309504880f;   // tan(pi/8)
    float r1 = ay - ax * T;
    float r2 = ax - ay * T;
    float eps = 1e-4f * (ax + ay);
    if (fabsf(r1) > eps && fabsf(r2) > eps) {
        if (r1 < 0.0f) return 0;
        if (r2 < 0.0f) return 2;
        return ((__float_as_uint(gx) ^ __float_as_uint(gy)) >> 31) ? 3 : 1;
    }
    return cls_fd(gy, gx);
}

static __device__ __forceinline__ void grad_g1v(float x00, float x01, float x02,
                                                float x10, float x12,
                                                float x20, float x21, float x22,
                                                float& gx, float& gy) {
    #pragma clang fp contract(off)
    { float A = -x00; float B = x02 + (-x20); float C = 2.0f*x12; float D = -2.0f*x10;
      float E = A + B; float F = C + D; gx = (E + F) + x22; }
    { float A = -x00; float B = (-x02) + x20; float C = -2.0f*x01; float D = 2.0f*x21;
      float E = A + B; float F = C + D; gy = (E + F) + x22; }
}

// ---------- k1: register-rolling NMS, lane = output col j0+lane ----------
__global__ __launch_bounds__(256) void k_nms(const float* __restrict__ x,
                                             float* __restrict__ nms,
                                             unsigned int* __restrict__ smax) {
    const int lane = threadIdx.x;
    const int ty   = threadIdx.y;
    const int d    = blockIdx.z;
    const int j0   = blockIdx.x * 64;
    const int r0   = blockIdx.y * 128 + ty * 32;
    if (r0 >= MG) return;

    const float* xd = x + (size_t)d * HW * HW;
    float* nd = nms + (size_t)d * MG * MG;

    // main column (wrapped fetch, unwrapped store)
    const int cm = j0 + lane;
    int cw = cm - ((cm >= MG) ? MG : 0);
    const bool cok  = (unsigned)(cw - 1) < (unsigned)HW;
    const int  xcol = cok ? (cw - 1) : 0;
    const bool outL = (cm < MG);
    // halo column for lanes 0,1,62,63: cols j0-2, j0-1, j0+64, j0+65
    const bool hlane = (lane < 2) | (lane >= 62);
    int hc = j0 + ((lane < 2) ? (lane - 2) : (lane + 2));
    hc += (hc < 0) ? MG : 0;  hc -= (hc >= MG) ? MG : 0;
    const bool hok  = (unsigned)(hc - 1) < (unsigned)HW;
    const int  hcol = hok ? (hc - 1) : 0;
    const bool L0 = (lane == 0), L63 = (lane == 63);

    float xc[3], xl[3], xr[3];
    float h0[3], h1[3], h2[3], h3[3];
    float mg[3], ml[3], mr[3];
    int   cl[3];
    float tmax = 0.0f;

    #pragma unroll
    for (int k = 0; k < 36; ++k) {
        // ---- load x row r0-2+k (wrapped, zero ring) ----
        int R = r0 - 2 + k;
        R += (R < 0) ? MG : 0;  R -= (R >= MG) ? MG : 0;
        const bool rok = (unsigned)(R - 1) < (unsigned)HW;   // wave-uniform
        const float* rowp = xd + (size_t)(rok ? (R - 1) : 0) * HW;
        float xv = 0.0f, hv = 0.0f;
        if (rok & cok)          xv = rowp[xcol];
        if (hlane & rok & hok)  hv = rowp[hcol];

        const int s = k % 3;
        h0[s] = __shfl(hv, 0);  h1[s] = __shfl(hv, 1);
        h2[s] = __shfl(hv, 62); h3[s] = __shfl(hv, 63);
        float lv = __shfl_up(xv, 1);   lv = L0  ? h1[s] : lv;
        float rv = __shfl_down(xv, 1); rv = L63 ? h2[s] : rv;
        xc[s] = xv; xl[s] = lv; xr[s] = rv;

        // ---- mag/cls for mag row j = k-2 (grid row r0-1+j) ----
        if (k >= 2) {
            const int j  = k - 2;
            const int s0 = j % 3, s1 = (j + 1) % 3, s2 = (j + 2) % 3;
            float gx, gy;
            grad_g1v(xl[s0], xc[s0], xr[s0],
                     xl[s1],         xr[s1],
                     xl[s2], xc[s2], xr[s2], gx, gy);
            float m;
            {
                #pragma clang fp contract(off)
                float p = gx * gx;
                float q = gy * gy;
                m = sqrtf(p + q);
            }
            // extra mag: lane0 -> col j0-1, lane63 -> col j0+64 (others unused)
            float ea0 = L0 ? h0[s0] : xc[s0];
            float ea1 = L0 ? h0[s1] : xc[s1];
            float ea2 = L0 ? h0[s2] : xc[s2];
            float eb0 = L0 ? h1[s0] : h2[s0];
            float eb1 = L0 ? h1[s1] : h2[s1];
            float eb2 = L0 ? h1[s2] : h2[s2];
            float ec0 = L0 ? xc[s0] : h3[s0];
            float ec1 = L0 ? xc[s1] : h3[s1];
            float ec2 = L0 ? xc[s2] : h3[s2];
            float egx, egy;
            grad_g1v(ea0, eb0, ec0,
                     ea1,      ec1,
                     ea2, eb2, ec2, egx, egy);
            float em;
            {
                #pragma clang fp contract(off)
                float p = egx * egx;
                float q = egy * egy;
                em = sqrtf(p + q);
            }
            mg[j % 3] = m;
            float mlv = __shfl_up(m, 1);   mlv = L0  ? em : mlv;
            float mrv = __shfl_down(m, 1); mrv = L63 ? em : mrv;
            ml[j % 3] = mlv;
            mr[j % 3] = mrv;
            cl[j % 3] = classify(gx, gy);
        }

        // ---- NMS output row t = k-4 (grid row r0+t) ----
        if (k >= 4) {
            const int t = k - 4;
            const int row = r0 + t;
            const int sA = t % 3, sB = (t + 1) % 3, sC = (t + 2) % 3;
            float m = mg[sB];
            int   c = cl[sB];
            float a = (c == 0) ? ml[sB] : (c == 1) ? ml[sA] : (c == 2) ? mg[sA] : mr[sA];
            float b = (c == 0) ? mr[sB] : (c == 1) ? mr[sC] : (c == 2) ? mg[sC] : ml[sC];
            float v = (m >= a && m >= b) ? m : 0.0f;
            if ((row < MG) & outL) {
                nd[(size_t)row * MG + cm] = v;
                tmax = fmaxf(tmax, v);
            }
        }
    }

    for (int off = 32; off > 0; off >>= 1)
        tmax = fmaxf(tmax, __shfl_down(tmax, off, 64));
    if (lane == 0)
        atomicMax(smax + d, __float_as_uint(tmax));   // nonneg: uint order-preserving
}

// ---------- k2: thresholds + 3x3 strong-pool hysteresis + crop ----------
__global__ __launch_bounds__(256) void k_edges(const float* __restrict__ nms,
                                               const unsigned int* __restrict__ smax,
                                               float* __restrict__ out) {
    __shared__ float ns[18][67];
    const int tx = threadIdx.x, ty = threadIdx.y;
    const int d   = blockIdx.z;
    const int ys  = blockIdx.y * 16;
    const int xs0 = blockIdx.x * 64;
    const float* nd = nms + (size_t)d * MG * MG;

    #pragma unroll
    for (int k = 0; k < 5; ++k) {
        const int r = ty + 4 * k;
        if (r < 18) {
            const float* rp = nd + (size_t)(ys + r) * MG + xs0;
            ns[r][tx] = rp[tx];
            if (tx < 2) ns[r][tx + 64] = rp[tx + 64];
        }
    }
    __syncthreads();

    const float high = __uint_as_float(smax[d]) * 0.05f;
    const float low  = high * 0.01f;

    float* od = out + (size_t)d * HW * HW;
    #pragma unroll
    for (int q = 0; q < 4; ++q) {
        const int ry = ty + 4 * q;
        const int y = ys + ry, xo = xs0 + tx;
        const int r = ry + 1,  c  = tx + 1;
        float m = ns[r][c];
        float e;
        if (m >= high) {
            e = 1.0f;
        } else if (m >= low) {
            bool pooled =
                ns[r-1][c-1] >= high || ns[r-1][c] >= high || ns[r-1][c+1] >= high ||
                ns[r][c-1]   >= high ||                       ns[r][c+1]   >= high ||
                ns[r+1][c-1] >= high || ns[r+1][c] >= high || ns[r+1][c+1] >= high;
            e = pooled ? 1.0f : 0.0f;
        } else {
            e = 0.0f;
        }
        od[(size_t)y * HW + xo] = e;
    }
}

extern "C" void kernel_launch(void* const* d_in, const int* in_sizes, int n_in,
                              void* d_out, int out_size, void* d_ws, size_t ws_size,
                              hipStream_t stream) {
    const float* x = (const float*)d_in[0];
    float* out = (float*)d_out;
    float* nms = (float*)d_ws;                                   // 514*514*128*4 = 135.26 MB
    unsigned int* smax = (unsigned int*)((char*)d_ws + (size_t)DD * MG * MG * sizeof(float));

    hipMemsetAsync(smax, 0, DD * sizeof(unsigned int), stream);

    dim3 blk(64, 4, 1);
    k_nms  <<<dim3(9, 5, DD), blk, 0, stream>>>(x, nms, smax);   // 64-col x 32-row strips
    k_edges<<<dim3(8, 32, DD), blk, 0, stream>>>(nms, smax, out);
}

// Round 21
// 321.175 us; speedup vs baseline: 1.3001x; 1.3001x over previous
//
#include <hip/hip_runtime.h>
#include <math.h>

#define DD 128
#define HW 512
#define MG 514

// Verified reference stack (r10/r11/r14): G1 predux-tree colmajor conv,
// contract-off mul/add mag, fd-hybrid classifier.
// r21: two fused register-pipeline kernels, no intermediate buffer.
//   k_max1: per-slice max(mag)  [== max(nms): argmax-mag always survives NMS]
//   k_fused: mag->cls->NMS->threshold->hysteresis -> out (2048B-pitch rows:
//            every 256B store = 2 full cachelines, no write amplification)

static __device__ float fd_atanf(float x) {
    #pragma clang fp contract(off)
    const unsigned hx = __float_as_uint(x);
    const unsigned ix = hx & 0x7fffffffu;
    const double A0 = 0.46364760900080611621425623146121440203;
    const double A1 = 0.78539816339744830961566084581987572105;
    const double A2 = 0.98279372324732906798571061101466601449;
    const double A3 = 1.57079632679489661923132169163975144210;
    const float aT0 =  3.3333328366e-01f;
    const float aT1 = -1.9999158382e-01f;
    const float aT2 =  1.4253635705e-01f;
    const float aT3 = -1.0648017377e-01f;
    const float aT4 =  6.1687607318e-02f;
    float z, w, s1, s2;
    int id;
    double a;
    if (ix >= 0x4c800000u) {
        a = A3;
        float hi = (float)a; if ((double)hi > a) hi = __uint_as_float(__float_as_uint(hi) - 1u);
        float lo = (float)(a - (double)hi);
        float r = hi + lo;
        return (hx >> 31) ? -r : r;
    }
    if (ix < 0x3ee00000u) {
        if (ix < 0x39800000u) return x;
        id = -1;
    } else {
        x = fabsf(x);
        if (ix < 0x3f980000u) {
            if (ix < 0x3f300000u) { id = 0; x = (2.0f * x - 1.0f) / (2.0f + x); }
            else                  { id = 1; x = (x - 1.0f) / (x + 1.0f); }
        } else {
            if (ix < 0x401c0000u) { id = 2; x = (x - 1.5f) / (1.0f + 1.5f * x); }
            else                  { id = 3; x = -1.0f / x; }
        }
    }
    z = x * x;
    w = z * z;
    s1 = z * (aT0 + w * (aT2 + w * aT4));
    s2 = w * (aT1 + w * aT3);
    if (id < 0) return x - x * (s1 + s2);
    a = (id == 0) ? A0 : (id == 1) ? A1 : (id == 2) ? A2 : A3;
    float hi = (float)a; if ((double)hi > a) hi = __uint_as_float(__float_as_uint(hi) - 1u);
    float lo = (float)(a - (double)hi);
    z = hi - ((x * (s1 + s2) - lo) - x);
    return (hx >> 31) ? -z : z;
}

static __device__ __noinline__ int cls_fd(float y, float x) {
    #pragma clang fp contract(off)
    const unsigned hx = __float_as_uint(x), hy = __float_as_uint(y);
    const unsigned ix = hx & 0x7fffffffu, iy = hy & 0x7fffffffu;
    unsigned m = ((hy >> 31) & 1u) | ((hx >> 30) & 2u);
    const double PI_D = 3.14159265358979323846264338327950288420;
    const float pi_f  = (float)PI_D;
    const float pi_lo = (float)(PI_D - (double)pi_f);
    const float pi4_f = (float)(PI_D / 4.0);
    const float pi2_f = (float)(PI_D / 2.0);
    float v;
    if (iy == 0) {
        v = (m == 0 || m == 1) ? y : (m == 2 ? pi_f : -pi_f);
    } else if (ix == 0) {
        v = (m & 1u) ? -pi2_f : pi2_f;
    } else if (ix + (26u << 23) < iy) {
        v = (m & 1u) ? -pi2_f : pi2_f;
    } else {
        float z;
        if ((m & 2u) && iy + (26u << 23) < ix) z = 0.0f;
        else z = fd_atanf(fabsf(y / x));
        switch (m) {
            case 0:  v = z; break;
            case 1:  v = -z; break;
            case 2:  v = pi_f - (z - pi_lo); break;
            default: v = (z - pi_lo) - pi_f; break;
        }
    }
    float t = v / pi4_f;
    int n = (int)rintf(t);
    return n & 3;
}

static __device__ __forceinline__ int classify(float gx, float gy) {
    #pragma clang fp contract(off)
    float ax = fabsf(gx), ay = fabsf(gy);
    const float T = 0.41421356237309504880f;
    float r1 = ay - ax * T;
    float r2 = ax - ay * T;
    float eps = 1e-4f * (ax + ay);
    if (fabsf(r1) > eps && fabsf(r2) > eps) {
        if (r1 < 0.0f) return 0;
        if (r2 < 0.0f) return 2;
        return ((__float_as_uint(gx) ^ __float_as_uint(gy)) >> 31) ? 3 : 1;
    }
    return cls_fd(gy, gx);
}

static __device__ __forceinline__ void grad_g1v(float x00, float x01, float x02,
                                                float x10, float x12,
                                                float x20, float x21, float x22,
                                                float& gx, float& gy) {
    #pragma clang fp contract(off)
    { float A = -x00; float B = x02 + (-x20); float C = 2.0f*x12; float D = -2.0f*x10;
      float E = A + B; float F = C + D; gx = (E + F) + x22; }
    { float A = -x00; float B = (-x02) + x20; float C = -2.0f*x01; float D = 2.0f*x21;
      float E = A + B; float F = C + D; gy = (E + F) + x22; }
}

static __device__ __forceinline__ float mag2(float gx, float gy) {
    #pragma clang fp contract(off)
    float p = gx * gx;
    float q = gy * gy;
    return sqrtf(p + q);
}

// ---------- pass 1: per-slice max(mag) over full 514x514 grid ----------
__global__ __launch_bounds__(256) void k_max1(const float* __restrict__ x,
                                              unsigned int* __restrict__ smax) {
    const int lane = threadIdx.x, ty = threadIdx.y;
    const int d  = blockIdx.z;
    const int j0 = blockIdx.x * 64;                 // 0..512 (9 blocks)
    const int m0 = (blockIdx.y * 4 + ty) * 33;      // mag-row strip origin (16 strips)
    const float* xd = x + (size_t)d * HW * HW;

    const int  c   = j0 + lane;                      // grid col (may exceed 513)
    int cw = c - ((c >= MG) ? MG : 0);
    const bool cok   = (unsigned)(cw - 1) < (unsigned)HW;
    const int  colv  = cok ? (cw - 1) : 0;
    const bool cmask = (c <= 513);
    const bool L0 = (lane == 0), L63 = (lane == 63);
    const bool hl = L0 | L63;
    int hg = L0 ? (j0 - 1) : (j0 + 64);
    hg += (hg < 0) ? MG : 0;  hg -= (hg >= MG) ? MG : 0;
    const bool hok  = (unsigned)(hg - 1) < (unsigned)HW;
    const int  hcol = hok ? (hg - 1) : 0;

    float Xc[3], Xl[3], Xr[3];
    float acc = 0.0f;

    #pragma unroll
    for (int k = 0; k < 35; ++k) {
        int Rx = m0 - 1 + k;
        int W = Rx;  W += (W < 0) ? MG : 0;  W -= (W >= MG) ? MG : 0;
        float xv = 0.0f, hv = 0.0f;
        if ((unsigned)(W - 1) < (unsigned)HW) {
            const float* rowp = xd + (size_t)(W - 1) * HW;
            if (cok)      xv = rowp[colv];
            if (hl & hok) hv = rowp[hcol];
        }
        float bl = __shfl(hv, 0), br = __shfl(hv, 63);
        float xlv = __shfl_up(xv, 1);   if (L0)  xlv = bl;
        float xrv = __shfl_down(xv, 1); if (L63) xrv = br;
        const int s = k % 3;
        Xc[s] = xv; Xl[s] = xlv; Xr[s] = xrv;

        if (k >= 2) {
            const int Rm = m0 - 2 + k;
            if (Rm <= 513) {
                const int u0 = (s + 1) % 3, u1 = (s + 2) % 3, u2 = s;
                float gx, gy;
                grad_g1v(Xl[u0], Xc[u0], Xr[u0],
                         Xl[u1],         Xr[u1],
                         Xl[u2], Xc[u2], Xr[u2], gx, gy);
                float m = mag2(gx, gy);
                if (cmask) acc = fmaxf(acc, m);
            }
        }
    }
    for (int off = 32; off > 0; off >>= 1)
        acc = fmaxf(acc, __shfl_down(acc, off, 64));
    if (lane == 0)
        atomicMax(smax + d, __float_as_uint(acc));   // nonneg: uint order-preserving
}

// ---------- pass 2: fused mag/cls/NMS/threshold/hysteresis -> out ----------
#define P2BODY(kk, S, DO_MAG, DO_NMS, DO_OUT) do {                                    \
    constexpr int s_ = (S);                                                           \
    constexpr int sp1 = (s_ + 1) % 3, sp2 = (s_ + 2) % 3;                             \
    int Rx = h0 - 3 + (kk);                                                           \
    int W = Rx;  W += (W < 0) ? MG : 0;  W -= (W >= MG) ? MG : 0;                     \
    float xv = 0.0f, hv = 0.0f;                                                       \
    if ((unsigned)(W - 1) < (unsigned)HW) {                                           \
        const float* rowp = xd + (size_t)(W - 1) * HW;                                \
        xv = rowp[xcolM];                                                             \
        if (hland & hok) hv = rowp[hcolv];                                            \
    }                                                                                 \
    float hA = __shfl(hv, 0),  hB = __shfl(hv, 1),  hC = __shfl(hv, 2);               \
    float hD = __shfl(hv, 61), hE = __shfl(hv, 62), hF = __shfl(hv, 63);              \
    float xlv = __shfl_up(xv, 1);   if (L0)  xlv = hC;                                \
    float xrv = __shfl_down(xv, 1); if (L63) xrv = hD;                                \
    Xc[s_] = xv; Xl[s_] = xlv; Xr[s_] = xrv;                                          \
    E0[s_] = L0 ? hA : hD;  E1[s_] = L0 ? hB : hE;  E2[s_] = L0 ? hC : hF;            \
    if (DO_MAG) {                                                                     \
        constexpr int u0 = sp1, u1 = sp2, u2 = s_;                                    \
        float gx, gy;                                                                 \
        grad_g1v(Xl[u0], Xc[u0], Xr[u0], Xl[u1], Xr[u1], Xl[u2], Xc[u2], Xr[u2],      \
                 gx, gy);                                                             \
        float m = mag2(gx, gy);                                                       \
        float g1x, g1y;                                                               \
        grad_g1v(L0 ? E0[u0] : Xc[u0], L0 ? E1[u0] : E0[u0], L0 ? E2[u0] : E1[u0],    \
                 L0 ? E0[u1] : Xc[u1],                        L0 ? E2[u1] : E1[u1],   \
                 L0 ? E0[u2] : Xc[u2], L0 ? E1[u2] : E0[u2], L0 ? E2[u2] : E1[u2],    \
                 g1x, g1y);                                                           \
        float em1 = mag2(g1x, g1y);                                                   \
        float g2x, g2y;                                                               \
        grad_g1v(L0 ? E1[u0] : E0[u0], L0 ? E2[u0] : E1[u0], L0 ? Xc[u0] : E2[u0],    \
                 L0 ? E1[u1] : E0[u1],                        L0 ? Xc[u1] : E2[u1],   \
                 L0 ? E1[u2] : E0[u2], L0 ? E2[u2] : E1[u2], L0 ? Xc[u2] : E2[u2],    \
                 g2x, g2y);                                                           \
        float em2 = mag2(g2x, g2y);                                                   \
        float mlv = __shfl_up(m, 1);   if (L0)  mlv = em2;                            \
        float mrv = __shfl_down(m, 1); if (L63) mrv = em1;                            \
        Mc[sp1] = m; Ml[sp1] = mlv; Mr[sp1] = mrv;                                    \
        Emc[sp1] = L0 ? em2 : em1;                                                    \
        Eml[sp1] = L0 ? em1 : m;                                                      \
        Emr[sp1] = L0 ? m   : em2;                                                    \
        Cl[sp1]  = classify(gx, gy);                                                  \
        Ecl[sp1] = classify(L0 ? g2x : g1x, L0 ? g2y : g1y);                          \
    }                                                                                 \
    if (DO_NMS) {                                                                     \
        constexpr int w0 = sp2, w1 = s_, w2 = sp1;                                    \
        float m = Mc[w1]; int c = Cl[w1];                                             \
        float a = (c == 0) ? Ml[w1] : (c == 1) ? Ml[w0] : (c == 2) ? Mc[w0] : Mr[w0]; \
        float b = (c == 0) ? Mr[w1] : (c == 1) ? Mr[w2] : (c == 2) ? Mc[w2] : Ml[w2]; \
        float nv = (m >= a && m >= b) ? m : 0.0f;                                     \
        float eM = Emc[w1]; int ec = Ecl[w1];                                         \
        float ea = (ec == 0) ? Eml[w1] : (ec == 1) ? Eml[w0]                          \
                 : (ec == 2) ? Emc[w0] : Emr[w0];                                     \
        float eb = (ec == 0) ? Emr[w1] : (ec == 1) ? Emr[w2]                          \
                 : (ec == 2) ? Emc[w2] : Eml[w2];                                     \
        float env = (eM >= ea && eM >= eb) ? eM : 0.0f;                               \
        float nlv = __shfl_up(nv, 1);   if (L0)  nlv = env;                           \
        float nrv = __shfl_down(nv, 1); if (L63) nrv = env;                           \
        Nc[sp2] = nv; Nl[sp2] = nlv; Nr[sp2] = nrv;                                   \
    }                                                                                 \
    if (DO_OUT) {                                                                     \
        constexpr int z0 = s_, z1 = sp1, z2 = sp2;                                    \
        int Rh = h0 + (kk) - 6;                                                       \
        float m = Nc[z1];                                                             \
        float e;                                                                      \
        if (m >= high) e = 1.0f;                                                      \
        else if (m >= low) {                                                          \
            bool pooled = Nl[z0] >= high || Nc[z0] >= high || Nr[z0] >= high ||       \
                          Nl[z1] >= high ||                    Nr[z1] >= high ||      \
                          Nl[z2] >= high || Nc[z2] >= high || Nr[z2] >= high;         \
            e = pooled ? 1.0f : 0.0f;                                                 \
        } else e = 0.0f;                                                              \
        if (Rh <= 512) od[(size_t)(Rh - 1) * HW + cout] = e;                          \
    }                                                                                 \
} while (0)

__global__ __launch_bounds__(256) void k_fused(const float* __restrict__ x,
                                               const unsigned int* __restrict__ smax,
                                               float* __restrict__ out) {
    const int lane = threadIdx.x, ty = threadIdx.y;
    const int d  = blockIdx.z;
    const int j0 = blockIdx.x * 64;                    // 0..448 (8 blocks)
    const int h0 = 1 + (blockIdx.y * 4 + ty) * 33;     // out grid-row strip (16 strips)
    const float* xd = x + (size_t)d * HW * HW;
    float* od = out + (size_t)d * HW * HW;

    const int  cout  = j0 + lane;                      // out col, 0..511
    const int  xcolM = j0 + lane;                      // x col of grid col gcol-1 (always valid)
    const bool L0 = (lane == 0), L63 = (lane == 63);
    const bool hland = (lane < 3) | (lane >= 61);
    int hg = j0 + ((lane < 3) ? (lane - 2) : (lane + 4));
    hg += (hg < 0) ? MG : 0;  hg -= (hg >= MG) ? MG : 0;
    const bool hok   = (unsigned)(hg - 1) < (unsigned)HW;
    const int  hcolv = hok ? (hg - 1) : 0;

    const float high = __uint_as_float(smax[d]) * 0.05f;
    const float low  = high * 0.01f;

    float Xc[3], Xl[3], Xr[3], E0[3], E1[3], E2[3];
    float Mc[3], Ml[3], Mr[3], Emc[3], Eml[3], Emr[3];
    int   Cl[3], Ecl[3];
    float Nc[3], Nl[3], Nr[3];

    // prologue k = 0..5 (phases ramp in; constants fold)
    P2BODY(0, 0, 0, 0, 0);
    P2BODY(1, 1, 0, 0, 0);
    P2BODY(2, 2, 1, 0, 0);
    P2BODY(3, 0, 1, 0, 0);
    P2BODY(4, 1, 1, 1, 0);
    P2BODY(5, 2, 1, 1, 0);
    // main: k = 6..38 (33 out rows), slots static via 3-step macro-iter
    #pragma unroll 1
    for (int kb = 6; kb < 39; kb += 3) {
        P2BODY(kb + 0, 0, 1, 1, 1);
        P2BODY(kb + 1, 1, 1, 1, 1);
        P2BODY(kb + 2, 2, 1, 1, 1);
    }
}

extern "C" void kernel_launch(void* const* d_in, const int* in_sizes, int n_in,
                              void* d_out, int out_size, void* d_ws, size_t ws_size,
                              hipStream_t stream) {
    const float* x = (const float*)d_in[0];
    float* out = (float*)d_out;
    unsigned int* smax = (unsigned int*)d_ws;          // 128 * 4B only

    hipMemsetAsync(smax, 0, DD * sizeof(unsigned int), stream);

    dim3 blk(64, 4, 1);
    k_max1 <<<dim3(9, 4, DD), blk, 0, stream>>>(x, smax);
    k_fused<<<dim3(8, 4, DD), blk, 0, stream>>>(x, smax, out);
}

// Round 22
// 202.271 us; speedup vs baseline: 2.0643x; 1.5878x over previous
//
#include <hip/hip_runtime.h>
#include <math.h>

#define DD 128
#define HW 512
#define MG 514

// Verified reference stack (r10/r11/r14): G1 predux-tree colmajor conv,
// contract-off mul/add mag, fd-hybrid classifier.
// r22: 4 output columns per lane (256-wide tiles), float4 loads/stores,
// same edge machinery amortized 4x. Bit-identical arithmetic.

static __device__ float fd_atanf(float x) {
    #pragma clang fp contract(off)
    const unsigned hx = __float_as_uint(x);
    const unsigned ix = hx & 0x7fffffffu;
    const double A0 = 0.46364760900080611621425623146121440203;
    const double A1 = 0.78539816339744830961566084581987572105;
    const double A2 = 0.98279372324732906798571061101466601449;
    const double A3 = 1.57079632679489661923132169163975144210;
    const float aT0 =  3.3333328366e-01f;
    const float aT1 = -1.9999158382e-01f;
    const float aT2 =  1.4253635705e-01f;
    const float aT3 = -1.0648017377e-01f;
    const float aT4 =  6.1687607318e-02f;
    float z, w, s1, s2;
    int id;
    double a;
    if (ix >= 0x4c800000u) {
        a = A3;
        float hi = (float)a; if ((double)hi > a) hi = __uint_as_float(__float_as_uint(hi) - 1u);
        float lo = (float)(a - (double)hi);
        float r = hi + lo;
        return (hx >> 31) ? -r : r;
    }
    if (ix < 0x3ee00000u) {
        if (ix < 0x39800000u) return x;
        id = -1;
    } else {
        x = fabsf(x);
        if (ix < 0x3f980000u) {
            if (ix < 0x3f300000u) { id = 0; x = (2.0f * x - 1.0f) / (2.0f + x); }
            else                  { id = 1; x = (x - 1.0f) / (x + 1.0f); }
        } else {
            if (ix < 0x401c0000u) { id = 2; x = (x - 1.5f) / (1.0f + 1.5f * x); }
            else                  { id = 3; x = -1.0f / x; }
        }
    }
    z = x * x;
    w = z * z;
    s1 = z * (aT0 + w * (aT2 + w * aT4));
    s2 = w * (aT1 + w * aT3);
    if (id < 0) return x - x * (s1 + s2);
    a = (id == 0) ? A0 : (id == 1) ? A1 : (id == 2) ? A2 : A3;
    float hi = (float)a; if ((double)hi > a) hi = __uint_as_float(__float_as_uint(hi) - 1u);
    float lo = (float)(a - (double)hi);
    z = hi - ((x * (s1 + s2) - lo) - x);
    return (hx >> 31) ? -z : z;
}

static __device__ __noinline__ int cls_fd(float y, float x) {
    #pragma clang fp contract(off)
    const unsigned hx = __float_as_uint(x), hy = __float_as_uint(y);
    const unsigned ix = hx & 0x7fffffffu, iy = hy & 0x7fffffffu;
    unsigned m = ((hy >> 31) & 1u) | ((hx >> 30) & 2u);
    const double PI_D = 3.14159265358979323846264338327950288420;
    const float pi_f  = (float)PI_D;
    const float pi_lo = (float)(PI_D - (double)pi_f);
    const float pi4_f = (float)(PI_D / 4.0);
    const float pi2_f = (float)(PI_D / 2.0);
    float v;
    if (iy == 0) {
        v = (m == 0 || m == 1) ? y : (m == 2 ? pi_f : -pi_f);
    } else if (ix == 0) {
        v = (m & 1u) ? -pi2_f : pi2_f;
    } else if (ix + (26u << 23) < iy) {
        v = (m & 1u) ? -pi2_f : pi2_f;
    } else {
        float z;
        if ((m & 2u) && iy + (26u << 23) < ix) z = 0.0f;
        else z = fd_atanf(fabsf(y / x));
        switch (m) {
            case 0:  v = z; break;
            case 1:  v = -z; break;
            case 2:  v = pi_f - (z - pi_lo); break;
            default: v = (z - pi_lo) - pi_f; break;
        }
    }
    float t = v / pi4_f;
    int n = (int)rintf(t);
    return n & 3;
}

static __device__ __forceinline__ int classify(float gx, float gy) {
    #pragma clang fp contract(off)
    float ax = fabsf(gx), ay = fabsf(gy);
    const float T = 0.41421356237309504880f;
    float r1 = ay - ax * T;
    float r2 = ax - ay * T;
    float eps = 1e-4f * (ax + ay);
    if (fabsf(r1) > eps && fabsf(r2) > eps) {
        if (r1 < 0.0f) return 0;
        if (r2 < 0.0f) return 2;
        return ((__float_as_uint(gx) ^ __float_as_uint(gy)) >> 31) ? 3 : 1;
    }
    return cls_fd(gy, gx);
}

static __device__ __forceinline__ void grad_g1v(float x00, float x01, float x02,
                                                float x10, float x12,
                                                float x20, float x21, float x22,
                                                float& gx, float& gy) {
    #pragma clang fp contract(off)
    { float A = -x00; float B = x02 + (-x20); float C = 2.0f*x12; float D = -2.0f*x10;
      float E = A + B; float F = C + D; gx = (E + F) + x22; }
    { float A = -x00; float B = (-x02) + x20; float C = -2.0f*x01; float D = 2.0f*x21;
      float E = A + B; float F = C + D; gy = (E + F) + x22; }
}

static __device__ __forceinline__ float mag2(float gx, float gy) {
    #pragma clang fp contract(off)
    float p = gx * gx;
    float q = gy * gy;
    return sqrtf(p + q);
}

// common per-body load+mux (shared text between both kernels via macro)
#define LOADROW(S_, ROWEXPR) do {                                                     \
    int Rx_ = (ROWEXPR);                                                              \
    int W_ = Rx_;  W_ += (W_ < 0) ? MG : 0;  W_ -= (W_ >= MG) ? MG : 0;               \
    float4 xv_ = float4{0.f, 0.f, 0.f, 0.f}; float hv_ = 0.f;                         \
    if ((unsigned)(W_ - 1) < (unsigned)HW) {                                          \
        const float* rowp_ = xd + (size_t)(W_ - 1) * HW;                              \
        xv_ = *(const float4*)(rowp_ + j0 + 4 * lane);                                \
        if (hland && hok) hv_ = rowp_[hcolv];                                         \
    }                                                                                 \
    float hA_ = __shfl(hv_, 0),  hB_ = __shfl(hv_, 1),  hC_ = __shfl(hv_, 2);         \
    float hD_ = __shfl(hv_, 61), hE_ = __shfl(hv_, 62), hF_ = __shfl(hv_, 63);        \
    float xlv_ = __shfl_up(xv_.w, 1);   if (L0)  xlv_ = hC_;                          \
    float xrv_ = __shfl_down(xv_.x, 1); if (L63) xrv_ = hD_;                          \
    Xc0[S_] = xv_.x; Xc1[S_] = xv_.y; Xc2[S_] = xv_.z; Xc3[S_] = xv_.w;               \
    Xl[S_] = xlv_; Xr[S_] = xrv_;                                                     \
    E0[S_] = L0 ? hA_ : hD_; E1[S_] = L0 ? hB_ : hE_; E2[S_] = L0 ? hC_ : hF_;        \
} while (0)

// compute 4 main grads/mags + 2 edge grads/mags for rows (u0,u1,u2)
#define MAGS6(u0, u1, u2)                                                             \
    float gx0, gy0, gx1, gy1, gx2, gy2, gx3, gy3;                                     \
    grad_g1v(Xl[u0], Xc0[u0], Xc1[u0], Xl[u1], Xc1[u1],                               \
             Xl[u2], Xc0[u2], Xc1[u2], gx0, gy0);                                     \
    grad_g1v(Xc0[u0], Xc1[u0], Xc2[u0], Xc0[u1], Xc2[u1],                             \
             Xc0[u2], Xc1[u2], Xc2[u2], gx1, gy1);                                    \
    grad_g1v(Xc1[u0], Xc2[u0], Xc3[u0], Xc1[u1], Xc3[u1],                             \
             Xc1[u2], Xc2[u2], Xc3[u2], gx2, gy2);                                    \
    grad_g1v(Xc2[u0], Xc3[u0], Xr[u0], Xc2[u1], Xr[u1],                               \
             Xc2[u2], Xc3[u2], Xr[u2], gx3, gy3);                                     \
    float m0_ = mag2(gx0, gy0), m1_ = mag2(gx1, gy1);                                 \
    float m2_ = mag2(gx2, gy2), m3_ = mag2(gx3, gy3);                                 \
    float A0_ = L0 ? E0[u0] : Xc3[u0], B0_ = L0 ? E1[u0] : E0[u0];                    \
    float C0_ = L0 ? E2[u0] : E1[u0],  D0_ = L0 ? Xc0[u0] : E2[u0];                   \
    float A1_ = L0 ? E0[u1] : Xc3[u1], B1_ = L0 ? E1[u1] : E0[u1];                    \
    float C1_ = L0 ? E2[u1] : E1[u1],  D1_ = L0 ? Xc0[u1] : E2[u1];                   \
    float A2_ = L0 ? E0[u2] : Xc3[u2], B2_ = L0 ? E1[u2] : E0[u2];                    \
    float C2_ = L0 ? E2[u2] : E1[u2],  D2_ = L0 ? Xc0[u2] : E2[u2];                   \
    float g1x, g1y, g2x, g2y;                                                         \
    grad_g1v(A0_, B0_, C0_, A1_, C1_, A2_, B2_, C2_, g1x, g1y);                       \
    grad_g1v(B0_, C0_, D0_, B1_, D1_, B2_, C2_, D2_, g2x, g2y);                       \
    float em1 = mag2(g1x, g1y), em2 = mag2(g2x, g2y);

// ---------------- pass 1: per-slice max(mag) [== max(nms)] ----------------
#define M1BODY(kk, S, DOMAG) do {                                                     \
    constexpr int s_ = (S);                                                           \
    constexpr int u0 = (s_ + 1) % 3, u1 = (s_ + 2) % 3, u2 = s_;                      \
    LOADROW(s_, h0m - 1 + (kk));                                                      \
    if (DOMAG) {                                                                      \
        int Rm = h0m - 2 + (kk);                                                      \
        if (Rm <= 513) {                                                              \
            MAGS6(u0, u1, u2)                                                         \
            acc = fmaxf(acc, fmaxf(fmaxf(m0_, m1_), fmaxf(m2_, m3_)));                \
            if (L0 || L63) acc = fmaxf(acc, fmaxf(em1, em2));                         \
        }                                                                             \
    }                                                                                 \
} while (0)

__global__ __launch_bounds__(256) void k_max1(const float* __restrict__ x,
                                              unsigned int* __restrict__ smax) {
    const int lane = threadIdx.x, ty = threadIdx.y;
    const int d  = blockIdx.z;
    const int j0 = blockIdx.x * 256;                 // x-col base (0 or 256)
    const int h0m = (blockIdx.y * 4 + ty) * 17;      // mag-row strip (32 strips)
    const float* xd = x + (size_t)d * HW * HW;
    const bool L0 = (lane == 0), L63 = (lane == 63);
    const bool hland = (lane < 3) | (lane >= 61);
    int hg = j0 + ((lane < 3) ? (lane - 2) : (lane + 196));
    hg += (hg < 0) ? MG : 0;  hg -= (hg >= MG) ? MG : 0;
    const bool hok   = (unsigned)(hg - 1) < (unsigned)HW;
    const int  hcolv = hok ? (hg - 1) : 0;

    float Xc0[3], Xc1[3], Xc2[3], Xc3[3], Xl[3], Xr[3], E0[3], E1[3], E2[3];
    float acc = 0.0f;

    M1BODY(0, 0, 0); M1BODY(1, 1, 0);
    #pragma unroll 1
    for (int kb = 2; kb < 17; kb += 3) {
        M1BODY(kb + 0, 2, 1);
        M1BODY(kb + 1, 0, 1);
        M1BODY(kb + 2, 1, 1);
    }
    M1BODY(17, 2, 1); M1BODY(18, 0, 1);

    for (int off = 32; off > 0; off >>= 1)
        acc = fmaxf(acc, __shfl_down(acc, off, 64));
    if (lane == 0)
        atomicMax(smax + d, __float_as_uint(acc));   // nonneg: uint order-preserving
}

// ---------------- pass 2: fused mag/cls/NMS/threshold/hysteresis ----------------
#define P2BODY(kk, S, DO_MAG, DO_NMS, DO_OUT) do {                                    \
    constexpr int s_ = (S);                                                           \
    constexpr int sp1 = (s_ + 1) % 3, sp2 = (s_ + 2) % 3;                             \
    LOADROW(s_, h0 - 3 + (kk));                                                       \
    if (DO_MAG) {                                                                     \
        MAGS6(sp1, sp2, s_)                                                           \
        float mlv = __shfl_up(m3_, 1);   if (L0)  mlv = em2;                          \
        float mrv = __shfl_down(m0_, 1); if (L63) mrv = em1;                          \
        M0[sp1] = m0_; M1[sp1] = m1_; M2[sp1] = m2_; M3[sp1] = m3_;                   \
        Mlft[sp1] = mlv; Mrgt[sp1] = mrv;                                             \
        Emc[sp1] = L0 ? em2 : em1;                                                    \
        Eml[sp1] = L0 ? em1 : m3_;                                                    \
        Emr[sp1] = L0 ? m0_ : em2;                                                    \
        C0[sp1] = classify(gx0, gy0); C1[sp1] = classify(gx1, gy1);                   \
        C2[sp1] = classify(gx2, gy2); C3[sp1] = classify(gx3, gy3);                   \
        Ecl[sp1] = classify(L0 ? g2x : g1x, L0 ? g2y : g1y);                          \
    }                                                                                 \
    if (DO_NMS) {                                                                     \
        constexpr int w0 = sp2, w1 = s_, w2 = sp1;                                    \
        float n0_, n1_, n2_, n3_;                                                     \
        { float m = M0[w1]; int c = C0[w1];                                           \
          float a = (c==0)?Mlft[w1]:(c==1)?Mlft[w0]:(c==2)?M0[w0]:M1[w0];             \
          float b = (c==0)?M1[w1]:(c==1)?M1[w2]:(c==2)?M0[w2]:Mlft[w2];               \
          n0_ = (m >= a && m >= b) ? m : 0.0f; }                                      \
        { float m = M1[w1]; int c = C1[w1];                                           \
          float a = (c==0)?M0[w1]:(c==1)?M0[w0]:(c==2)?M1[w0]:M2[w0];                 \
          float b = (c==0)?M2[w1]:(c==1)?M2[w2]:(c==2)?M1[w2]:M0[w2];                 \
          n1_ = (m >= a && m >= b) ? m : 0.0f; }                                      \
        { float m = M2[w1]; int c = C2[w1];                                           \
          float a = (c==0)?M1[w1]:(c==1)?M1[w0]:(c==2)?M2[w0]:M3[w0];                 \
          float b = (c==0)?M3[w1]:(c==1)?M3[w2]:(c==2)?M2[w2]:M1[w2];                 \
          n2_ = (m >= a && m >= b) ? m : 0.0f; }                                      \
        { float m = M3[w1]; int c = C3[w1];                                           \
          float a = (c==0)?M2[w1]:(c==1)?M2[w0]:(c==2)?M3[w0]:Mrgt[w0];               \
          float b = (c==0)?Mrgt[w1]:(c==1)?Mrgt[w2]:(c==2)?M3[w2]:M2[w2];             \
          n3_ = (m >= a && m >= b) ? m : 0.0f; }                                      \
        float env;                                                                    \
        { float m = Emc[w1]; int c = Ecl[w1];                                         \
          float a = (c==0)?Eml[w1]:(c==1)?Eml[w0]:(c==2)?Emc[w0]:Emr[w0];             \
          float b = (c==0)?Emr[w1]:(c==1)?Emr[w2]:(c==2)?Emc[w2]:Eml[w2];             \
          env = (m >= a && m >= b) ? m : 0.0f; }                                      \
        float nlv = __shfl_up(n3_, 1);   if (L0)  nlv = env;                          \
        float nrv = __shfl_down(n0_, 1); if (L63) nrv = env;                          \
        N0[sp2] = n0_; N1[sp2] = n1_; N2[sp2] = n2_; N3[sp2] = n3_;                   \
        Nl[sp2] = nlv; Nr[sp2] = nrv;                                                 \
    }                                                                                 \
    if (DO_OUT) {                                                                     \
        constexpr int z0 = s_, z1 = sp1, z2 = sp2;                                    \
        int Rh = h0 + (kk) - 6;                                                       \
        float4 e4;                                                                    \
        { float m = N0[z1]; float e;                                                  \
          if (m >= high) e = 1.0f;                                                    \
          else if (m >= low) {                                                        \
            bool p = Nl[z0]>=high || N0[z0]>=high || N1[z0]>=high ||                  \
                     Nl[z1]>=high ||                  N1[z1]>=high ||                 \
                     Nl[z2]>=high || N0[z2]>=high || N1[z2]>=high;                    \
            e = p ? 1.0f : 0.0f; } else e = 0.0f;                                     \
          e4.x = e; }                                                                 \
        { float m = N1[z1]; float e;                                                  \
          if (m >= high) e = 1.0f;                                                    \
          else if (m >= low) {                                                        \
            bool p = N0[z0]>=high || N1[z0]>=high || N2[z0]>=high ||                  \
                     N0[z1]>=high ||                  N2[z1]>=high ||                 \
                     N0[z2]>=high || N1[z2]>=high || N2[z2]>=high;                    \
            e = p ? 1.0f : 0.0f; } else e = 0.0f;                                     \
          e4.y = e; }                                                                 \
        { float m = N2[z1]; float e;                                                  \
          if (m >= high) e = 1.0f;                                                    \
          else if (m >= low) {                                                        \
            bool p = N1[z0]>=high || N2[z0]>=high || N3[z0]>=high ||                  \
                     N1[z1]>=high ||                  N3[z1]>=high ||                 \
                     N1[z2]>=high || N2[z2]>=high || N3[z2]>=high;                    \
            e = p ? 1.0f : 0.0f; } else e = 0.0f;                                     \
          e4.z = e; }                                                                 \
        { float m = N3[z1]; float e;                                                  \
          if (m >= high) e = 1.0f;                                                    \
          else if (m >= low) {                                                        \
            bool p = N2[z0]>=high || N3[z0]>=high || Nr[z0]>=high ||                  \
                     N2[z1]>=high ||                  Nr[z1]>=high ||                 \
                     N2[z2]>=high || N3[z2]>=high || Nr[z2]>=high;                    \
            e = p ? 1.0f : 0.0f; } else e = 0.0f;                                     \
          e4.w = e; }                                                                 \
        *(float4*)(od + (size_t)(Rh - 1) * HW + j0 + 4 * lane) = e4;                  \
    }                                                                                 \
} while (0)

__global__ __launch_bounds__(256) void k_fused(const float* __restrict__ x,
                                               const unsigned int* __restrict__ smax,
                                               float* __restrict__ out) {
    const int lane = threadIdx.x, ty = threadIdx.y;
    const int d  = blockIdx.z;
    const int j0 = blockIdx.x * 256;                   // x/out col base (0 or 256)
    const int h0 = 1 + (blockIdx.y * 4 + ty) * 32;     // out grid-row strip (16 strips)
    const float* xd = x + (size_t)d * HW * HW;
    float* od = out + (size_t)d * HW * HW;
    const bool L0 = (lane == 0), L63 = (lane == 63);
    const bool hland = (lane < 3) | (lane >= 61);
    int hg = j0 + ((lane < 3) ? (lane - 2) : (lane + 196));
    hg += (hg < 0) ? MG : 0;  hg -= (hg >= MG) ? MG : 0;
    const bool hok   = (unsigned)(hg - 1) < (unsigned)HW;
    const int  hcolv = hok ? (hg - 1) : 0;

    const float high = __uint_as_float(smax[d]) * 0.05f;
    const float low  = high * 0.01f;

    float Xc0[3], Xc1[3], Xc2[3], Xc3[3], Xl[3], Xr[3], E0[3], E1[3], E2[3];
    float M0[3], M1[3], M2[3], M3[3], Mlft[3], Mrgt[3], Emc[3], Eml[3], Emr[3];
    int   C0[3], C1[3], C2[3], C3[3], Ecl[3];
    float N0[3], N1[3], N2[3], N3[3], Nl[3], Nr[3];

    P2BODY(0, 0, 0, 0, 0);
    P2BODY(1, 1, 0, 0, 0);
    P2BODY(2, 2, 1, 0, 0);
    P2BODY(3, 0, 1, 0, 0);
    P2BODY(4, 1, 1, 1, 0);
    P2BODY(5, 2, 1, 1, 0);
    #pragma unroll 1
    for (int kb = 6; kb < 36; kb += 3) {
        P2BODY(kb + 0, 0, 1, 1, 1);
        P2BODY(kb + 1, 1, 1, 1, 1);
        P2BODY(kb + 2, 2, 1, 1, 1);
    }
    P2BODY(36, 0, 1, 1, 1);
    P2BODY(37, 1, 1, 1, 1);
}

extern "C" void kernel_launch(void* const* d_in, const int* in_sizes, int n_in,
                              void* d_out, int out_size, void* d_ws, size_t ws_size,
                              hipStream_t stream) {
    const float* x = (const float*)d_in[0];
    float* out = (float*)d_out;
    unsigned int* smax = (unsigned int*)d_ws;          // 128 * 4B only

    hipMemsetAsync(smax, 0, DD * sizeof(unsigned int), stream);

    dim3 blk(64, 4, 1);
    k_max1 <<<dim3(2, 8, DD), blk, 0, stream>>>(x, smax);
    k_fused<<<dim3(2, 4, DD), blk, 0, stream>>>(x, smax, out);
}

// Round 23
// 182.749 us; speedup vs baseline: 2.2848x; 1.1068x over previous
//
#include <hip/hip_runtime.h>
#include <math.h>

#define DD 128
#define HW 512
#define MG 514

// Verified reference stack (r10/r11/r14): G1 predux-tree colmajor conv,
// contract-off mul/add mag, fd-hybrid classifier.
// r23: k_fused 16-row strips (2x blocks, occupancy), k_max1 deferred sqrt
// (monotone => bit-exact). Arithmetic otherwise identical to r22.

static __device__ float fd_atanf(float x) {
    #pragma clang fp contract(off)
    const unsigned hx = __float_as_uint(x);
    const unsigned ix = hx & 0x7fffffffu;
    const double A0 = 0.46364760900080611621425623146121440203;
    const double A1 = 0.78539816339744830961566084581987572105;
    const double A2 = 0.98279372324732906798571061101466601449;
    const double A3 = 1.57079632679489661923132169163975144210;
    const float aT0 =  3.3333328366e-01f;
    const float aT1 = -1.9999158382e-01f;
    const float aT2 =  1.4253635705e-01f;
    const float aT3 = -1.0648017377e-01f;
    const float aT4 =  6.1687607318e-02f;
    float z, w, s1, s2;
    int id;
    double a;
    if (ix >= 0x4c800000u) {
        a = A3;
        float hi = (float)a; if ((double)hi > a) hi = __uint_as_float(__float_as_uint(hi) - 1u);
        float lo = (float)(a - (double)hi);
        float r = hi + lo;
        return (hx >> 31) ? -r : r;
    }
    if (ix < 0x3ee00000u) {
        if (ix < 0x39800000u) return x;
        id = -1;
    } else {
        x = fabsf(x);
        if (ix < 0x3f980000u) {
            if (ix < 0x3f300000u) { id = 0; x = (2.0f * x - 1.0f) / (2.0f + x); }
            else                  { id = 1; x = (x - 1.0f) / (x + 1.0f); }
        } else {
            if (ix < 0x401c0000u) { id = 2; x = (x - 1.5f) / (1.0f + 1.5f * x); }
            else                  { id = 3; x = -1.0f / x; }
        }
    }
    z = x * x;
    w = z * z;
    s1 = z * (aT0 + w * (aT2 + w * aT4));
    s2 = w * (aT1 + w * aT3);
    if (id < 0) return x - x * (s1 + s2);
    a = (id == 0) ? A0 : (id == 1) ? A1 : (id == 2) ? A2 : A3;
    float hi = (float)a; if ((double)hi > a) hi = __uint_as_float(__float_as_uint(hi) - 1u);
    float lo = (float)(a - (double)hi);
    z = hi - ((x * (s1 + s2) - lo) - x);
    return (hx >> 31) ? -z : z;
}

static __device__ __noinline__ int cls_fd(float y, float x) {
    #pragma clang fp contract(off)
    const unsigned hx = __float_as_uint(x), hy = __float_as_uint(y);
    const unsigned ix = hx & 0x7fffffffu, iy = hy & 0x7fffffffu;
    unsigned m = ((hy >> 31) & 1u) | ((hx >> 30) & 2u);
    const double PI_D = 3.14159265358979323846264338327950288420;
    const float pi_f  = (float)PI_D;
    const float pi_lo = (float)(PI_D - (double)pi_f);
    const float pi4_f = (float)(PI_D / 4.0);
    const float pi2_f = (float)(PI_D / 2.0);
    float v;
    if (iy == 0) {
        v = (m == 0 || m == 1) ? y : (m == 2 ? pi_f : -pi_f);
    } else if (ix == 0) {
        v = (m & 1u) ? -pi2_f : pi2_f;
    } else if (ix + (26u << 23) < iy) {
        v = (m & 1u) ? -pi2_f : pi2_f;
    } else {
        float z;
        if ((m & 2u) && iy + (26u << 23) < ix) z = 0.0f;
        else z = fd_atanf(fabsf(y / x));
        switch (m) {
            case 0:  v = z; break;
            case 1:  v = -z; break;
            case 2:  v = pi_f - (z - pi_lo); break;
            default: v = (z - pi_lo) - pi_f; break;
        }
    }
    float t = v / pi4_f;
    int n = (int)rintf(t);
    return n & 3;
}

static __device__ __forceinline__ int classify(float gx, float gy) {
    #pragma clang fp contract(off)
    float ax = fabsf(gx), ay = fabsf(gy);
    const float T = 0.41421356237309504880f;
    float r1 = ay - ax * T;
    float r2 = ax - ay * T;
    float eps = 1e-4f * (ax + ay);
    if (fabsf(r1) > eps && fabsf(r2) > eps) {
        if (r1 < 0.0f) return 0;
        if (r2 < 0.0f) return 2;
        return ((__float_as_uint(gx) ^ __float_as_uint(gy)) >> 31) ? 3 : 1;
    }
    return cls_fd(gy, gx);
}

static __device__ __forceinline__ void grad_g1v(float x00, float x01, float x02,
                                                float x10, float x12,
                                                float x20, float x21, float x22,
                                                float& gx, float& gy) {
    #pragma clang fp contract(off)
    { float A = -x00; float B = x02 + (-x20); float C = 2.0f*x12; float D = -2.0f*x10;
      float E = A + B; float F = C + D; gx = (E + F) + x22; }
    { float A = -x00; float B = (-x02) + x20; float C = -2.0f*x01; float D = 2.0f*x21;
      float E = A + B; float F = C + D; gy = (E + F) + x22; }
}

static __device__ __forceinline__ float mag2(float gx, float gy) {
    #pragma clang fp contract(off)
    float p = gx * gx;
    float q = gy * gy;
    return sqrtf(p + q);
}
static __device__ __forceinline__ float sq2(float gx, float gy) {   // pre-sqrt value
    #pragma clang fp contract(off)
    float p = gx * gx;
    float q = gy * gy;
    return p + q;
}

#define LOADROW(S_, ROWEXPR) do {                                                     \
    int Rx_ = (ROWEXPR);                                                              \
    int W_ = Rx_;  W_ += (W_ < 0) ? MG : 0;  W_ -= (W_ >= MG) ? MG : 0;               \
    float4 xv_ = float4{0.f, 0.f, 0.f, 0.f}; float hv_ = 0.f;                         \
    if ((unsigned)(W_ - 1) < (unsigned)HW) {                                          \
        const float* rowp_ = xd + (size_t)(W_ - 1) * HW;                              \
        xv_ = *(const float4*)(rowp_ + j0 + 4 * lane);                                \
        if (hland && hok) hv_ = rowp_[hcolv];                                         \
    }                                                                                 \
    float hA_ = __shfl(hv_, 0),  hB_ = __shfl(hv_, 1),  hC_ = __shfl(hv_, 2);         \
    float hD_ = __shfl(hv_, 61), hE_ = __shfl(hv_, 62), hF_ = __shfl(hv_, 63);        \
    float xlv_ = __shfl_up(xv_.w, 1);   if (L0)  xlv_ = hC_;                          \
    float xrv_ = __shfl_down(xv_.x, 1); if (L63) xrv_ = hD_;                          \
    Xc0[S_] = xv_.x; Xc1[S_] = xv_.y; Xc2[S_] = xv_.z; Xc3[S_] = xv_.w;               \
    Xl[S_] = xlv_; Xr[S_] = xrv_;                                                     \
    E0[S_] = L0 ? hA_ : hD_; E1[S_] = L0 ? hB_ : hE_; E2[S_] = L0 ? hC_ : hF_;        \
} while (0)

// 4 main grads + 2 edge grads; MAGFN applied to each
#define MAGS6_F(u0, u1, u2, MAGFN)                                                    \
    float gx0, gy0, gx1, gy1, gx2, gy2, gx3, gy3;                                     \
    grad_g1v(Xl[u0], Xc0[u0], Xc1[u0], Xl[u1], Xc1[u1],                               \
             Xl[u2], Xc0[u2], Xc1[u2], gx0, gy0);                                     \
    grad_g1v(Xc0[u0], Xc1[u0], Xc2[u0], Xc0[u1], Xc2[u1],                             \
             Xc0[u2], Xc1[u2], Xc2[u2], gx1, gy1);                                    \
    grad_g1v(Xc1[u0], Xc2[u0], Xc3[u0], Xc1[u1], Xc3[u1],                             \
             Xc1[u2], Xc2[u2], Xc3[u2], gx2, gy2);                                    \
    grad_g1v(Xc2[u0], Xc3[u0], Xr[u0], Xc2[u1], Xr[u1],                               \
             Xc2[u2], Xc3[u2], Xr[u2], gx3, gy3);                                     \
    float m0_ = MAGFN(gx0, gy0), m1_ = MAGFN(gx1, gy1);                               \
    float m2_ = MAGFN(gx2, gy2), m3_ = MAGFN(gx3, gy3);                               \
    float A0_ = L0 ? E0[u0] : Xc3[u0], B0_ = L0 ? E1[u0] : E0[u0];                    \
    float C0_ = L0 ? E2[u0] : E1[u0],  D0_ = L0 ? Xc0[u0] : E2[u0];                   \
    float A1_ = L0 ? E0[u1] : Xc3[u1], B1_ = L0 ? E1[u1] : E0[u1];                    \
    float C1_ = L0 ? E2[u1] : E1[u1],  D1_ = L0 ? Xc0[u1] : E2[u1];                   \
    float A2_ = L0 ? E0[u2] : Xc3[u2], B2_ = L0 ? E1[u2] : E0[u2];                    \
    float C2_ = L0 ? E2[u2] : E1[u2],  D2_ = L0 ? Xc0[u2] : E2[u2];                   \
    float g1x, g1y, g2x, g2y;                                                         \
    grad_g1v(A0_, B0_, C0_, A1_, C1_, A2_, B2_, C2_, g1x, g1y);                       \
    grad_g1v(B0_, C0_, D0_, B1_, D1_, B2_, C2_, D2_, g2x, g2y);                       \
    float em1 = MAGFN(g1x, g1y), em2 = MAGFN(g2x, g2y);

// ---------------- pass 1: per-slice max of (gx^2+gy^2); sqrt once ----------------
#define M1BODY(kk, S, DOMAG) do {                                                     \
    constexpr int s_ = (S);                                                           \
    constexpr int u0 = (s_ + 1) % 3, u1 = (s_ + 2) % 3, u2 = s_;                      \
    LOADROW(s_, h0m - 1 + (kk));                                                      \
    if (DOMAG) {                                                                      \
        int Rm = h0m - 2 + (kk);                                                      \
        if (Rm <= 513) {                                                              \
            MAGS6_F(u0, u1, u2, sq2)                                                  \
            acc = fmaxf(acc, fmaxf(fmaxf(m0_, m1_), fmaxf(m2_, m3_)));                \
            if (L0 || L63) acc = fmaxf(acc, fmaxf(em1, em2));                         \
        }                                                                             \
    }                                                                                 \
} while (0)

__global__ __launch_bounds__(256) void k_max1(const float* __restrict__ x,
                                              unsigned int* __restrict__ smax) {
    const int lane = threadIdx.x, ty = threadIdx.y;
    const int d  = blockIdx.z;
    const int j0 = blockIdx.x * 256;
    const int h0m = (blockIdx.y * 4 + ty) * 17;
    const float* xd = x + (size_t)d * HW * HW;
    const bool L0 = (lane == 0), L63 = (lane == 63);
    const bool hland = (lane < 3) | (lane >= 61);
    int hg = j0 + ((lane < 3) ? (lane - 2) : (lane + 196));
    hg += (hg < 0) ? MG : 0;  hg -= (hg >= MG) ? MG : 0;
    const bool hok   = (unsigned)(hg - 1) < (unsigned)HW;
    const int  hcolv = hok ? (hg - 1) : 0;

    float Xc0[3], Xc1[3], Xc2[3], Xc3[3], Xl[3], Xr[3], E0[3], E1[3], E2[3];
    float acc = 0.0f;

    M1BODY(0, 0, 0); M1BODY(1, 1, 0);
    #pragma unroll 1
    for (int kb = 2; kb < 17; kb += 3) {
        M1BODY(kb + 0, 2, 1);
        M1BODY(kb + 1, 0, 1);
        M1BODY(kb + 2, 1, 1);
    }
    M1BODY(17, 2, 1); M1BODY(18, 0, 1);

    for (int off = 32; off > 0; off >>= 1)
        acc = fmaxf(acc, __shfl_down(acc, off, 64));
    if (lane == 0) {
        float mx = sqrtf(acc);   // CR sqrt monotone: sqrt(max sq) == max(sqrt sq)
        atomicMax(smax + d, __float_as_uint(mx));
    }
}

// ---------------- pass 2: fused mag/cls/NMS/threshold/hysteresis ----------------
#define P2BODY(kk, S, DO_MAG, DO_NMS, DO_OUT) do {                                    \
    constexpr int s_ = (S);                                                           \
    constexpr int sp1 = (s_ + 1) % 3, sp2 = (s_ + 2) % 3;                             \
    LOADROW(s_, h0 - 3 + (kk));                                                       \
    if (DO_MAG) {                                                                     \
        MAGS6_F(sp1, sp2, s_, mag2)                                                   \
        float mlv = __shfl_up(m3_, 1);   if (L0)  mlv = em2;                          \
        float mrv = __shfl_down(m0_, 1); if (L63) mrv = em1;                          \
        M0[sp1] = m0_; M1[sp1] = m1_; M2[sp1] = m2_; M3[sp1] = m3_;                   \
        Mlft[sp1] = mlv; Mrgt[sp1] = mrv;                                             \
        Emc[sp1] = L0 ? em2 : em1;                                                    \
        Eml[sp1] = L0 ? em1 : m3_;                                                    \
        Emr[sp1] = L0 ? m0_ : em2;                                                    \
        C0[sp1] = classify(gx0, gy0); C1[sp1] = classify(gx1, gy1);                   \
        C2[sp1] = classify(gx2, gy2); C3[sp1] = classify(gx3, gy3);                   \
        Ecl[sp1] = classify(L0 ? g2x : g1x, L0 ? g2y : g1y);                          \
    }                                                                                 \
    if (DO_NMS) {                                                                     \
        constexpr int w0 = sp2, w1 = s_, w2 = sp1;                                    \
        float n0_, n1_, n2_, n3_;                                                     \
        { float m = M0[w1]; int c = C0[w1];                                           \
          float a = (c==0)?Mlft[w1]:(c==1)?Mlft[w0]:(c==2)?M0[w0]:M1[w0];             \
          float b = (c==0)?M1[w1]:(c==1)?M1[w2]:(c==2)?M0[w2]:Mlft[w2];               \
          n0_ = (m >= a && m >= b) ? m : 0.0f; }                                      \
        { float m = M1[w1]; int c = C1[w1];                                           \
          float a = (c==0)?M0[w1]:(c==1)?M0[w0]:(c==2)?M1[w0]:M2[w0];                 \
          float b = (c==0)?M2[w1]:(c==1)?M2[w2]:(c==2)?M1[w2]:M0[w2];                 \
          n1_ = (m >= a && m >= b) ? m : 0.0f; }                                      \
        { float m = M2[w1]; int c = C2[w1];                                           \
          float a = (c==0)?M1[w1]:(c==1)?M1[w0]:(c==2)?M2[w0]:M3[w0];                 \
          float b = (c==0)?M3[w1]:(c==1)?M3[w2]:(c==2)?M2[w2]:M1[w2];                 \
          n2_ = (m >= a && m >= b) ? m : 0.0f; }                                      \
        { float m = M3[w1]; int c = C3[w1];                                           \
          float a = (c==0)?M2[w1]:(c==1)?M2[w0]:(c==2)?M3[w0]:Mrgt[w0];               \
          float b = (c==0)?Mrgt[w1]:(c==1)?Mrgt[w2]:(c==2)?M3[w2]:M2[w2];             \
          n3_ = (m >= a && m >= b) ? m : 0.0f; }                                      \
        float env;                                                                    \
        { float m = Emc[w1]; int c = Ecl[w1];                                         \
          float a = (c==0)?Eml[w1]:(c==1)?Eml[w0]:(c==2)?Emc[w0]:Emr[w0];             \
          float b = (c==0)?Emr[w1]:(c==1)?Emr[w2]:(c==2)?Emc[w2]:Eml[w2];             \
          env = (m >= a && m >= b) ? m : 0.0f; }                                      \
        float nlv = __shfl_up(n3_, 1);   if (L0)  nlv = env;                          \
        float nrv = __shfl_down(n0_, 1); if (L63) nrv = env;                          \
        N0[sp2] = n0_; N1[sp2] = n1_; N2[sp2] = n2_; N3[sp2] = n3_;                   \
        Nl[sp2] = nlv; Nr[sp2] = nrv;                                                 \
    }                                                                                 \
    if (DO_OUT) {                                                                     \
        constexpr int z0 = s_, z1 = sp1, z2 = sp2;                                    \
        int Rh = h0 + (kk) - 6;                                                       \
        float4 e4;                                                                    \
        { float m = N0[z1]; float e;                                                  \
          if (m >= high) e = 1.0f;                                                    \
          else if (m >= low) {                                                        \
            bool p = Nl[z0]>=high || N0[z0]>=high || N1[z0]>=high ||                  \
                     Nl[z1]>=high ||                  N1[z1]>=high ||                 \
                     Nl[z2]>=high || N0[z2]>=high || N1[z2]>=high;                    \
            e = p ? 1.0f : 0.0f; } else e = 0.0f;                                     \
          e4.x = e; }                                                                 \
        { float m = N1[z1]; float e;                                                  \
          if (m >= high) e = 1.0f;                                                    \
          else if (m >= low) {                                                        \
            bool p = N0[z0]>=high || N1[z0]>=high || N2[z0]>=high ||                  \
                     N0[z1]>=high ||                  N2[z1]>=high ||                 \
                     N0[z2]>=high || N1[z2]>=high || N2[z2]>=high;                    \
            e = p ? 1.0f : 0.0f; } else e = 0.0f;                                     \
          e4.y = e; }                                                                 \
        { float m = N2[z1]; float e;                                                  \
          if (m >= high) e = 1.0f;                                                    \
          else if (m >= low) {                                                        \
            bool p = N1[z0]>=high || N2[z0]>=high || N3[z0]>=high ||                  \
                     N1[z1]>=high ||                  N3[z1]>=high ||                 \
                     N1[z2]>=high || N2[z2]>=high || N3[z2]>=high;                    \
            e = p ? 1.0f : 0.0f; } else e = 0.0f;                                     \
          e4.z = e; }                                                                 \
        { float m = N3[z1]; float e;                                                  \
          if (m >= high) e = 1.0f;                                                    \
          else if (m >= low) {                                                        \
            bool p = N2[z0]>=high || N3[z0]>=high || Nr[z0]>=high ||                  \
                     N2[z1]>=high ||                  Nr[z1]>=high ||                 \
                     N2[z2]>=high || N3[z2]>=high || Nr[z2]>=high;                    \
            e = p ? 1.0f : 0.0f; } else e = 0.0f;                                     \
          e4.w = e; }                                                                 \
        *(float4*)(od + (size_t)(Rh - 1) * HW + j0 + 4 * lane) = e4;                  \
    }                                                                                 \
} while (0)

__global__ __launch_bounds__(256) void k_fused(const float* __restrict__ x,
                                               const unsigned int* __restrict__ smax,
                                               float* __restrict__ out) {
    const int lane = threadIdx.x, ty = threadIdx.y;
    const int d  = blockIdx.z;
    const int j0 = blockIdx.x * 256;                   // x/out col base (0 or 256)
    const int h0 = 1 + (blockIdx.y * 4 + ty) * 16;     // out grid-row strip (32 strips)
    const float* xd = x + (size_t)d * HW * HW;
    float* od = out + (size_t)d * HW * HW;
    const bool L0 = (lane == 0), L63 = (lane == 63);
    const bool hland = (lane < 3) | (lane >= 61);
    int hg = j0 + ((lane < 3) ? (lane - 2) : (lane + 196));
    hg += (hg < 0) ? MG : 0;  hg -= (hg >= MG) ? MG : 0;
    const bool hok   = (unsigned)(hg - 1) < (unsigned)HW;
    const int  hcolv = hok ? (hg - 1) : 0;

    const float high = __uint_as_float(smax[d]) * 0.05f;
    const float low  = high * 0.01f;

    float Xc0[3], Xc1[3], Xc2[3], Xc3[3], Xl[3], Xr[3], E0[3], E1[3], E2[3];
    float M0[3], M1[3], M2[3], M3[3], Mlft[3], Mrgt[3], Emc[3], Eml[3], Emr[3];
    int   C0[3], C1[3], C2[3], C3[3], Ecl[3];
    float N0[3], N1[3], N2[3], N3[3], Nl[3], Nr[3];

    P2BODY(0, 0, 0, 0, 0);
    P2BODY(1, 1, 0, 0, 0);
    P2BODY(2, 2, 1, 0, 0);
    P2BODY(3, 0, 1, 0, 0);
    P2BODY(4, 1, 1, 1, 0);
    P2BODY(5, 2, 1, 1, 0);
    #pragma unroll 1
    for (int kb = 6; kb < 21; kb += 3) {
        P2BODY(kb + 0, 0, 1, 1, 1);
        P2BODY(kb + 1, 1, 1, 1, 1);
        P2BODY(kb + 2, 2, 1, 1, 1);
    }
    P2BODY(21, 0, 1, 1, 1);
}

extern "C" void kernel_launch(void* const* d_in, const int* in_sizes, int n_in,
                              void* d_out, int out_size, void* d_ws, size_t ws_size,
                              hipStream_t stream) {
    const float* x = (const float*)d_in[0];
    float* out = (float*)d_out;
    unsigned int* smax = (unsigned int*)d_ws;          // 128 * 4B only

    hipMemsetAsync(smax, 0, DD * sizeof(unsigned int), stream);

    dim3 blk(64, 4, 1);
    k_max1 <<<dim3(2, 8, DD), blk, 0, stream>>>(x, smax);
    k_fused<<<dim3(2, 8, DD), blk, 0, stream>>>(x, smax, out);
}

// Round 24
// 167.677 us; speedup vs baseline: 2.4902x; 1.0899x over previous
//
#include <hip/hip_runtime.h>
#include <math.h>

#define DD 128
#define HW 512
#define MG 514

// Verified reference stack (r10/r11/r14): G1 predux-tree colmajor conv,
// contract-off mul/add mag, fd-hybrid classifier.
// r24: geometry tuning only — k_fused 22-row strips (1536 blocks = exactly
// 6/CU), k_max1 33-row strips + full unroll. Arithmetic identical to r23.

static __device__ float fd_atanf(float x) {
    #pragma clang fp contract(off)
    const unsigned hx = __float_as_uint(x);
    const unsigned ix = hx & 0x7fffffffu;
    const double A0 = 0.46364760900080611621425623146121440203;
    const double A1 = 0.78539816339744830961566084581987572105;
    const double A2 = 0.98279372324732906798571061101466601449;
    const double A3 = 1.57079632679489661923132169163975144210;
    const float aT0 =  3.3333328366e-01f;
    const float aT1 = -1.9999158382e-01f;
    const float aT2 =  1.4253635705e-01f;
    const float aT3 = -1.0648017377e-01f;
    const float aT4 =  6.1687607318e-02f;
    float z, w, s1, s2;
    int id;
    double a;
    if (ix >= 0x4c800000u) {
        a = A3;
        float hi = (float)a; if ((double)hi > a) hi = __uint_as_float(__float_as_uint(hi) - 1u);
        float lo = (float)(a - (double)hi);
        float r = hi + lo;
        return (hx >> 31) ? -r : r;
    }
    if (ix < 0x3ee00000u) {
        if (ix < 0x39800000u) return x;
        id = -1;
    } else {
        x = fabsf(x);
        if (ix < 0x3f980000u) {
            if (ix < 0x3f300000u) { id = 0; x = (2.0f * x - 1.0f) / (2.0f + x); }
            else                  { id = 1; x = (x - 1.0f) / (x + 1.0f); }
        } else {
            if (ix < 0x401c0000u) { id = 2; x = (x - 1.5f) / (1.0f + 1.5f * x); }
            else                  { id = 3; x = -1.0f / x; }
        }
    }
    z = x * x;
    w = z * z;
    s1 = z * (aT0 + w * (aT2 + w * aT4));
    s2 = w * (aT1 + w * aT3);
    if (id < 0) return x - x * (s1 + s2);
    a = (id == 0) ? A0 : (id == 1) ? A1 : (id == 2) ? A2 : A3;
    float hi = (float)a; if ((double)hi > a) hi = __uint_as_float(__float_as_uint(hi) - 1u);
    float lo = (float)(a - (double)hi);
    z = hi - ((x * (s1 + s2) - lo) - x);
    return (hx >> 31) ? -z : z;
}

static __device__ __noinline__ int cls_fd(float y, float x) {
    #pragma clang fp contract(off)
    const unsigned hx = __float_as_uint(x), hy = __float_as_uint(y);
    const unsigned ix = hx & 0x7fffffffu, iy = hy & 0x7fffffffu;
    unsigned m = ((hy >> 31) & 1u) | ((hx >> 30) & 2u);
    const double PI_D = 3.14159265358979323846264338327950288420;
    const float pi_f  = (float)PI_D;
    const float pi_lo = (float)(PI_D - (double)pi_f);
    const float pi4_f = (float)(PI_D / 4.0);
    const float pi2_f = (float)(PI_D / 2.0);
    float v;
    if (iy == 0) {
        v = (m == 0 || m == 1) ? y : (m == 2 ? pi_f : -pi_f);
    } else if (ix == 0) {
        v = (m & 1u) ? -pi2_f : pi2_f;
    } else if (ix + (26u << 23) < iy) {
        v = (m & 1u) ? -pi2_f : pi2_f;
    } else {
        float z;
        if ((m & 2u) && iy + (26u << 23) < ix) z = 0.0f;
        else z = fd_atanf(fabsf(y / x));
        switch (m) {
            case 0:  v = z; break;
            case 1:  v = -z; break;
            case 2:  v = pi_f - (z - pi_lo); break;
            default: v = (z - pi_lo) - pi_f; break;
        }
    }
    float t = v / pi4_f;
    int n = (int)rintf(t);
    return n & 3;
}

static __device__ __forceinline__ int classify(float gx, float gy) {
    #pragma clang fp contract(off)
    float ax = fabsf(gx), ay = fabsf(gy);
    const float T = 0.41421356237309504880f;
    float r1 = ay - ax * T;
    float r2 = ax - ay * T;
    float eps = 1e-4f * (ax + ay);
    if (fabsf(r1) > eps && fabsf(r2) > eps) {
        if (r1 < 0.0f) return 0;
        if (r2 < 0.0f) return 2;
        return ((__float_as_uint(gx) ^ __float_as_uint(gy)) >> 31) ? 3 : 1;
    }
    return cls_fd(gy, gx);
}

static __device__ __forceinline__ void grad_g1v(float x00, float x01, float x02,
                                                float x10, float x12,
                                                float x20, float x21, float x22,
                                                float& gx, float& gy) {
    #pragma clang fp contract(off)
    { float A = -x00; float B = x02 + (-x20); float C = 2.0f*x12; float D = -2.0f*x10;
      float E = A + B; float F = C + D; gx = (E + F) + x22; }
    { float A = -x00; float B = (-x02) + x20; float C = -2.0f*x01; float D = 2.0f*x21;
      float E = A + B; float F = C + D; gy = (E + F) + x22; }
}

static __device__ __forceinline__ float mag2(float gx, float gy) {
    #pragma clang fp contract(off)
    float p = gx * gx;
    float q = gy * gy;
    return sqrtf(p + q);
}
static __device__ __forceinline__ float sq2(float gx, float gy) {
    #pragma clang fp contract(off)
    float p = gx * gx;
    float q = gy * gy;
    return p + q;
}

#define LOADROW(S_, ROWEXPR) do {                                                     \
    int Rx_ = (ROWEXPR);                                                              \
    int W_ = Rx_;  W_ += (W_ < 0) ? MG : 0;  W_ -= (W_ >= MG) ? MG : 0;               \
    float4 xv_ = float4{0.f, 0.f, 0.f, 0.f}; float hv_ = 0.f;                         \
    if ((unsigned)(W_ - 1) < (unsigned)HW) {                                          \
        const float* rowp_ = xd + (size_t)(W_ - 1) * HW;                              \
        xv_ = *(const float4*)(rowp_ + j0 + 4 * lane);                                \
        if (hland && hok) hv_ = rowp_[hcolv];                                         \
    }                                                                                 \
    float hA_ = __shfl(hv_, 0),  hB_ = __shfl(hv_, 1),  hC_ = __shfl(hv_, 2);         \
    float hD_ = __shfl(hv_, 61), hE_ = __shfl(hv_, 62), hF_ = __shfl(hv_, 63);        \
    float xlv_ = __shfl_up(xv_.w, 1);   if (L0)  xlv_ = hC_;                          \
    float xrv_ = __shfl_down(xv_.x, 1); if (L63) xrv_ = hD_;                          \
    Xc0[S_] = xv_.x; Xc1[S_] = xv_.y; Xc2[S_] = xv_.z; Xc3[S_] = xv_.w;               \
    Xl[S_] = xlv_; Xr[S_] = xrv_;                                                     \
    E0[S_] = L0 ? hA_ : hD_; E1[S_] = L0 ? hB_ : hE_; E2[S_] = L0 ? hC_ : hF_;        \
} while (0)

#define MAGS6_F(u0, u1, u2, MAGFN)                                                    \
    float gx0, gy0, gx1, gy1, gx2, gy2, gx3, gy3;                                     \
    grad_g1v(Xl[u0], Xc0[u0], Xc1[u0], Xl[u1], Xc1[u1],                               \
             Xl[u2], Xc0[u2], Xc1[u2], gx0, gy0);                                     \
    grad_g1v(Xc0[u0], Xc1[u0], Xc2[u0], Xc0[u1], Xc2[u1],                             \
             Xc0[u2], Xc1[u2], Xc2[u2], gx1, gy1);                                    \
    grad_g1v(Xc1[u0], Xc2[u0], Xc3[u0], Xc1[u1], Xc3[u1],                             \
             Xc1[u2], Xc2[u2], Xc3[u2], gx2, gy2);                                    \
    grad_g1v(Xc2[u0], Xc3[u0], Xr[u0], Xc2[u1], Xr[u1],                               \
             Xc2[u2], Xc3[u2], Xr[u2], gx3, gy3);                                     \
    float m0_ = MAGFN(gx0, gy0), m1_ = MAGFN(gx1, gy1);                               \
    float m2_ = MAGFN(gx2, gy2), m3_ = MAGFN(gx3, gy3);                               \
    float A0_ = L0 ? E0[u0] : Xc3[u0], B0_ = L0 ? E1[u0] : E0[u0];                    \
    float C0_ = L0 ? E2[u0] : E1[u0],  D0_ = L0 ? Xc0[u0] : E2[u0];                   \
    float A1_ = L0 ? E0[u1] : Xc3[u1], B1_ = L0 ? E1[u1] : E0[u1];                    \
    float C1_ = L0 ? E2[u1] : E1[u1],  D1_ = L0 ? Xc0[u1] : E2[u1];                   \
    float A2_ = L0 ? E0[u2] : Xc3[u2], B2_ = L0 ? E1[u2] : E0[u2];                    \
    float C2_ = L0 ? E2[u2] : E1[u2],  D2_ = L0 ? Xc0[u2] : E2[u2];                   \
    float g1x, g1y, g2x, g2y;                                                         \
    grad_g1v(A0_, B0_, C0_, A1_, C1_, A2_, B2_, C2_, g1x, g1y);                       \
    grad_g1v(B0_, C0_, D0_, B1_, D1_, B2_, C2_, D2_, g2x, g2y);                       \
    float em1 = MAGFN(g1x, g1y), em2 = MAGFN(g2x, g2y);

// ---------------- pass 1: per-slice max of (gx^2+gy^2); sqrt once ----------------
#define M1BODY(kk, S, DOMAG) do {                                                     \
    constexpr int s_ = (S);                                                           \
    constexpr int u0 = (s_ + 1) % 3, u1 = (s_ + 2) % 3, u2 = s_;                      \
    LOADROW(s_, h0m - 1 + (kk));                                                      \
    if (DOMAG) {                                                                      \
        int Rm = h0m - 2 + (kk);                                                      \
        if (Rm <= 513) {                                                              \
            MAGS6_F(u0, u1, u2, sq2)                                                  \
            acc = fmaxf(acc, fmaxf(fmaxf(m0_, m1_), fmaxf(m2_, m3_)));                \
            if (L0 || L63) acc = fmaxf(acc, fmaxf(em1, em2));                         \
        }                                                                             \
    }                                                                                 \
} while (0)

__global__ __launch_bounds__(256) void k_max1(const float* __restrict__ x,
                                              unsigned int* __restrict__ smax) {
    const int lane = threadIdx.x, ty = threadIdx.y;
    const int d  = blockIdx.z;
    const int j0 = blockIdx.x * 256;
    const int h0m = (blockIdx.y * 4 + ty) * 33;      // 16 strips x 33 mag rows
    const float* xd = x + (size_t)d * HW * HW;
    const bool L0 = (lane == 0), L63 = (lane == 63);
    const bool hland = (lane < 3) | (lane >= 61);
    int hg = j0 + ((lane < 3) ? (lane - 2) : (lane + 196));
    hg += (hg < 0) ? MG : 0;  hg -= (hg >= MG) ? MG : 0;
    const bool hok   = (unsigned)(hg - 1) < (unsigned)HW;
    const int  hcolv = hok ? (hg - 1) : 0;

    float Xc0[3], Xc1[3], Xc2[3], Xc3[3], Xl[3], Xr[3], E0[3], E1[3], E2[3];
    float acc = 0.0f;

    M1BODY(0, 0, 0); M1BODY(1, 1, 0);
    #pragma unroll
    for (int kb = 2; kb < 35; kb += 3) {             // 11 triples: kk = 2..34
        M1BODY(kb + 0, 2, 1);
        M1BODY(kb + 1, 0, 1);
        M1BODY(kb + 2, 1, 1);
    }

    for (int off = 32; off > 0; off >>= 1)
        acc = fmaxf(acc, __shfl_down(acc, off, 64));
    if (lane == 0) {
        float mx = sqrtf(acc);   // CR sqrt monotone: sqrt(max sq) == max(sqrt sq)
        atomicMax(smax + d, __float_as_uint(mx));
    }
}

// ---------------- pass 2: fused mag/cls/NMS/threshold/hysteresis ----------------
#define P2BODY(kk, S, DO_MAG, DO_NMS, DO_OUT) do {                                    \
    constexpr int s_ = (S);                                                           \
    constexpr int sp1 = (s_ + 1) % 3, sp2 = (s_ + 2) % 3;                             \
    LOADROW(s_, h0 - 3 + (kk));                                                       \
    if (DO_MAG) {                                                                     \
        MAGS6_F(sp1, sp2, s_, mag2)                                                   \
        float mlv = __shfl_up(m3_, 1);   if (L0)  mlv = em2;                          \
        float mrv = __shfl_down(m0_, 1); if (L63) mrv = em1;                          \
        M0[sp1] = m0_; M1[sp1] = m1_; M2[sp1] = m2_; M3[sp1] = m3_;                   \
        Mlft[sp1] = mlv; Mrgt[sp1] = mrv;                                             \
        Emc[sp1] = L0 ? em2 : em1;                                                    \
        Eml[sp1] = L0 ? em1 : m3_;                                                    \
        Emr[sp1] = L0 ? m0_ : em2;                                                    \
        C0[sp1] = classify(gx0, gy0); C1[sp1] = classify(gx1, gy1);                   \
        C2[sp1] = classify(gx2, gy2); C3[sp1] = classify(gx3, gy3);                   \
        Ecl[sp1] = classify(L0 ? g2x : g1x, L0 ? g2y : g1y);                          \
    }                                                                                 \
    if (DO_NMS) {                                                                     \
        constexpr int w0 = sp2, w1 = s_, w2 = sp1;                                    \
        float n0_, n1_, n2_, n3_;                                                     \
        { float m = M0[w1]; int c = C0[w1];                                           \
          float a = (c==0)?Mlft[w1]:(c==1)?Mlft[w0]:(c==2)?M0[w0]:M1[w0];             \
          float b = (c==0)?M1[w1]:(c==1)?M1[w2]:(c==2)?M0[w2]:Mlft[w2];               \
          n0_ = (m >= a && m >= b) ? m : 0.0f; }                                      \
        { float m = M1[w1]; int c = C1[w1];                                           \
          float a = (c==0)?M0[w1]:(c==1)?M0[w0]:(c==2)?M1[w0]:M2[w0];                 \
          float b = (c==0)?M2[w1]:(c==1)?M2[w2]:(c==2)?M1[w2]:M0[w2];                 \
          n1_ = (m >= a && m >= b) ? m : 0.0f; }                                      \
        { float m = M2[w1]; int c = C2[w1];                                           \
          float a = (c==0)?M1[w1]:(c==1)?M1[w0]:(c==2)?M2[w0]:M3[w0];                 \
          float b = (c==0)?M3[w1]:(c==1)?M3[w2]:(c==2)?M2[w2]:M1[w2];                 \
          n2_ = (m >= a && m >= b) ? m : 0.0f; }                                      \
        { float m = M3[w1]; int c = C3[w1];                                           \
          float a = (c==0)?M2[w1]:(c==1)?M2[w0]:(c==2)?M3[w0]:Mrgt[w0];               \
          float b = (c==0)?Mrgt[w1]:(c==1)?Mrgt[w2]:(c==2)?M3[w2]:M2[w2];             \
          n3_ = (m >= a && m >= b) ? m : 0.0f; }                                      \
        float env;                                                                    \
        { float m = Emc[w1]; int c = Ecl[w1];                                         \
          float a = (c==0)?Eml[w1]:(c==1)?Eml[w0]:(c==2)?Emc[w0]:Emr[w0];             \
          float b = (c==0)?Emr[w1]:(c==1)?Emr[w2]:(c==2)?Emc[w2]:Eml[w2];             \
          env = (m >= a && m >= b) ? m : 0.0f; }                                      \
        float nlv = __shfl_up(n3_, 1);   if (L0)  nlv = env;                          \
        float nrv = __shfl_down(n0_, 1); if (L63) nrv = env;                          \
        N0[sp2] = n0_; N1[sp2] = n1_; N2[sp2] = n2_; N3[sp2] = n3_;                   \
        Nl[sp2] = nlv; Nr[sp2] = nrv;                                                 \
    }                                                                                 \
    if (DO_OUT) {                                                                     \
        constexpr int z0 = s_, z1 = sp1, z2 = sp2;                                    \
        int Rh = h0 + (kk) - 6;                                                       \
        float4 e4;                                                                    \
        { float m = N0[z1]; float e;                                                  \
          if (m >= high) e = 1.0f;                                                    \
          else if (m >= low) {                                                        \
            bool p = Nl[z0]>=high || N0[z0]>=high || N1[z0]>=high ||                  \
                     Nl[z1]>=high ||                  N1[z1]>=high ||                 \
                     Nl[z2]>=high || N0[z2]>=high || N1[z2]>=high;                    \
            e = p ? 1.0f : 0.0f; } else e = 0.0f;                                     \
          e4.x = e; }                                                                 \
        { float m = N1[z1]; float e;                                                  \
          if (m >= high) e = 1.0f;                                                    \
          else if (m >= low) {                                                        \
            bool p = N0[z0]>=high || N1[z0]>=high || N2[z0]>=high ||                  \
                     N0[z1]>=high ||                  N2[z1]>=high ||                 \
                     N0[z2]>=high || N1[z2]>=high || N2[z2]>=high;                    \
            e = p ? 1.0f : 0.0f; } else e = 0.0f;                                     \
          e4.y = e; }                                                                 \
        { float m = N2[z1]; float e;                                                  \
          if (m >= high) e = 1.0f;                                                    \
          else if (m >= low) {                                                        \
            bool p = N1[z0]>=high || N2[z0]>=high || N3[z0]>=high ||                  \
                     N1[z1]>=high ||                  N3[z1]>=high ||                 \
                     N1[z2]>=high || N2[z2]>=high || N3[z2]>=high;                    \
            e = p ? 1.0f : 0.0f; } else e = 0.0f;                                     \
          e4.z = e; }                                                                 \
        { float m = N3[z1]; float e;                                                  \
          if (m >= high) e = 1.0f;                                                    \
          else if (m >= low) {                                                        \
            bool p = N2[z0]>=high || N3[z0]>=high || Nr[z0]>=high ||                  \
                     N2[z1]>=high ||                  Nr[z1]>=high ||                 \
                     N2[z2]>=high || N3[z2]>=high || Nr[z2]>=high;                    \
            e = p ? 1.0f : 0.0f; } else e = 0.0f;                                     \
          e4.w = e; }                                                                 \
        if (Rh <= 512)                                                                \
            *(float4*)(od + (size_t)(Rh - 1) * HW + j0 + 4 * lane) = e4;              \
    }                                                                                 \
} while (0)

__global__ __launch_bounds__(256) void k_fused(const float* __restrict__ x,
                                               const unsigned int* __restrict__ smax,
                                               float* __restrict__ out) {
    const int lane = threadIdx.x, ty = threadIdx.y;
    const int d  = blockIdx.z;
    const int j0 = blockIdx.x * 256;                   // x/out col base (0 or 256)
    const int h0 = 1 + (blockIdx.y * 4 + ty) * 22;     // 24 strips x 22 out rows
    const float* xd = x + (size_t)d * HW * HW;
    float* od = out + (size_t)d * HW * HW;
    const bool L0 = (lane == 0), L63 = (lane == 63);
    const bool hland = (lane < 3) | (lane >= 61);
    int hg = j0 + ((lane < 3) ? (lane - 2) : (lane + 196));
    hg += (hg < 0) ? MG : 0;  hg -= (hg >= MG) ? MG : 0;
    const bool hok   = (unsigned)(hg - 1) < (unsigned)HW;
    const int  hcolv = hok ? (hg - 1) : 0;

    const float high = __uint_as_float(smax[d]) * 0.05f;
    const float low  = high * 0.01f;

    float Xc0[3], Xc1[3], Xc2[3], Xc3[3], Xl[3], Xr[3], E0[3], E1[3], E2[3];
    float M0[3], M1[3], M2[3], M3[3], Mlft[3], Mrgt[3], Emc[3], Eml[3], Emr[3];
    int   C0[3], C1[3], C2[3], C3[3], Ecl[3];
    float N0[3], N1[3], N2[3], N3[3], Nl[3], Nr[3];

    P2BODY(0, 0, 0, 0, 0);
    P2BODY(1, 1, 0, 0, 0);
    P2BODY(2, 2, 1, 0, 0);
    P2BODY(3, 0, 1, 0, 0);
    P2BODY(4, 1, 1, 1, 0);
    P2BODY(5, 2, 1, 1, 0);
    #pragma unroll 1
    for (int kb = 6; kb < 27; kb += 3) {               // kk = 6..26
        P2BODY(kb + 0, 0, 1, 1, 1);
        P2BODY(kb + 1, 1, 1, 1, 1);
        P2BODY(kb + 2, 2, 1, 1, 1);
    }
    P2BODY(27, 0, 1, 1, 1);                            // t = 21 (last row of strip)
}

extern "C" void kernel_launch(void* const* d_in, const int* in_sizes, int n_in,
                              void* d_out, int out_size, void* d_ws, size_t ws_size,
                              hipStream_t stream) {
    const float* x = (const float*)d_in[0];
    float* out = (float*)d_out;
    unsigned int* smax = (unsigned int*)d_ws;          // 128 * 4B only

    hipMemsetAsync(smax, 0, DD * sizeof(unsigned int), stream);

    dim3 blk(64, 4, 1);
    k_max1 <<<dim3(2, 4, DD), blk, 0, stream>>>(x, smax);
    k_fused<<<dim3(2, 6, DD), blk, 0, stream>>>(x, smax, out);
}